// Round 9
// baseline (40780.667 us; speedup 1.0000x reference)
//
#include <hip/hip_runtime.h>
#include <hip/hip_bf16.h>

#define Bq 64
#define Tq 512
#define Eq 128
#define Hq 256
#define NTAGS 50
#define Mq (Bq*Tq)   // 32768

__device__ __forceinline__ float sigmoidf_(float x) { return 1.f / (1.f + expf(-x)); }

// ---------------- init: zero h-state + barrier counters ----------------
__global__ void init_kernel(float* H1, float* H2, unsigned* cnt) {
    int i = blockIdx.x * blockDim.x + threadIdx.x;
    const int n = 2 * 2 * Bq * Hq;
    if (i < n) { H1[i] = 0.f; H2[i] = 0.f; }
    if (i < 32) cnt[i] = 0u;
}

// ---------------- dtype detection: int32 vs int64 for words/lengths ----------------
__global__ void detect_int64(const unsigned* __restrict__ words,
                             const unsigned* __restrict__ lens,
                             unsigned* __restrict__ dflags) {
    __shared__ int wbad, lbad, wnz, lnz;
    if (threadIdx.x == 0) { wbad = 0; lbad = 0; wnz = 0; lnz = 0; }
    __syncthreads();
    for (int i = threadIdx.x; i < 16384; i += blockDim.x) {
        if (words[2 * i + 1] != 0u) wbad = 1;
        if (words[2 * i] != 0u) wnz = 1;
    }
    for (int i = threadIdx.x; i < 32; i += blockDim.x) {
        if (lens[2 * i + 1] != 0u) lbad = 1;
        if (lens[2 * i] != 0u) lnz = 1;
    }
    __syncthreads();
    if (threadIdx.x == 0) {
        unsigned f = 0;
        if (!wbad && wnz) f |= 1u;
        if (!lbad && lnz) f |= 2u;
        dflags[0] = f;
    }
}

// ---------------- bias: bias[l][d][n] = bih + bhh ----------------
__global__ void bias_kernel(const float* b1f_ih, const float* b1f_hh,
                            const float* b1b_ih, const float* b1b_hh,
                            const float* b2f_ih, const float* b2f_hh,
                            const float* b2b_ih, const float* b2b_hh,
                            float* bias) {   // [4][1024]: l1f,l1b,l2f,l2b
    int i = blockIdx.x * blockDim.x + threadIdx.x;
    if (i >= 4096) return;
    int l = i >> 11, d = (i >> 10) & 1, nn = i & 1023;
    float v;
    if (l == 0) v = d ? (b1b_ih[nn] + b1b_hh[nn]) : (b1f_ih[nn] + b1f_hh[nn]);
    else        v = d ? (b2b_ih[nn] + b2b_hh[nn]) : (b2f_ih[nn] + b2f_hh[nn]);
    bias[i] = v;
}

// ---------------- f32 GEMM: C[M,N] = A[M,K] @ W[N,K]^T + bias ----------------
// AMODE: 0 = A f32, 2 = A gathered from emb via words (dtype-adaptive), 3 = A f16
// OUTT:  0 = f32, 1 = f16
template<int AMODE, int OUTT>
__global__ __launch_bounds__(256)
void gemm_kernel(const void* __restrict__ Aptr, const unsigned* __restrict__ words_u32,
                 const float* __restrict__ emb, const unsigned* __restrict__ dflags,
                 const float* __restrict__ Wlo, const float* __restrict__ Whi,
                 const float* __restrict__ blo, const float* __restrict__ bhi,
                 void* __restrict__ Cptr, int M, int N, int K)
{
    __shared__ float As[16][68];
    __shared__ float Ws[16][68];
    const int tx = threadIdx.x & 15, ty = threadIdx.x >> 4;
    const int m0 = blockIdx.y * 64, n0 = blockIdx.x * 64;
    const bool hi = ((m0 & 511) >= 256);
    const float* W = hi ? Whi : Wlo;
    const float* bias = hi ? bhi : blo;
    const int lr = threadIdx.x >> 2, lc = threadIdx.x & 3;
    bool w64 = false;
    if (AMODE == 2) w64 = (dflags[0] & 1u) != 0u;
    float acc[4][4] = {};
    for (int k0 = 0; k0 < K; k0 += 16) {
        float a4[4], w4[4];
        if (AMODE == 2) {
            int m = m0 + lr;
            int w = (int)(w64 ? words_u32[2 * m] : words_u32[m]);
            float4 v = *(const float4*)(emb + (size_t)w * Eq + k0 + lc * 4);
            a4[0] = v.x; a4[1] = v.y; a4[2] = v.z; a4[3] = v.w;
        } else if (AMODE == 0) {
            float4 v = *(const float4*)((const float*)Aptr + (size_t)(m0 + lr) * K + k0 + lc * 4);
            a4[0] = v.x; a4[1] = v.y; a4[2] = v.z; a4[3] = v.w;
        } else {
            const _Float16* Ab = (const _Float16*)Aptr + (size_t)(m0 + lr) * K + k0 + lc * 4;
            #pragma unroll
            for (int q = 0; q < 4; ++q) a4[q] = (float)Ab[q];
        }
        int nrow = n0 + lr;
        if (nrow < N) {
            float4 v = *(const float4*)(W + (size_t)nrow * K + k0 + lc * 4);
            w4[0] = v.x; w4[1] = v.y; w4[2] = v.z; w4[3] = v.w;
        } else { w4[0] = w4[1] = w4[2] = w4[3] = 0.f; }
        __syncthreads();
        #pragma unroll
        for (int q = 0; q < 4; ++q) {
            As[lc * 4 + q][lr] = a4[q];
            Ws[lc * 4 + q][lr] = w4[q];
        }
        __syncthreads();
        #pragma unroll
        for (int kk = 0; kk < 16; ++kk) {
            float4 a = *(const float4*)&As[kk][ty * 4];
            float4 w = *(const float4*)&Ws[kk][tx * 4];
            float av[4] = {a.x, a.y, a.z, a.w};
            float wv[4] = {w.x, w.y, w.z, w.w};
            #pragma unroll
            for (int i = 0; i < 4; ++i)
                #pragma unroll
                for (int j = 0; j < 4; ++j)
                    acc[i][j] += av[i] * wv[j];
        }
    }
    #pragma unroll
    for (int i = 0; i < 4; ++i) {
        int row = m0 + ty * 4 + i;
        #pragma unroll
        for (int j = 0; j < 4; ++j) {
            int col = n0 + tx * 4 + j;
            if (col < N) {
                float v = acc[i][j] + bias[col];
                if (OUTT == 1) ((_Float16*)Cptr)[(size_t)row * N + col] = (_Float16)v;
                else           ((float*)Cptr)[(size_t)row * N + col] = v;
            }
        }
    }
}

// ---------------- persistent BiLSTM layer (Whh in LDS, barrier h-exchange) ----------------
// grid = 128 blocks: bid = bs*16 + dir*8 + js
//   dir: direction, js: hidden slice (32 units), bs: batch slice (8 elems)
// Groups of 8 blocks (same dir,bs) exchange h via Hst[par][dir][b][k] with
// relaxed agent-scope atomics ordered by an acq-rel counter barrier.
// OUTT: 0 = f32, 1 = f16
template<int OUTT>
__global__ __launch_bounds__(512)
void lstm_layer(const float* __restrict__ xg,             // [M][1024] phased
                const float* __restrict__ Whh_f, const float* __restrict__ Whh_b, // [1024][256]
                const unsigned* __restrict__ len_u32,
                const unsigned* __restrict__ dflags,
                float* __restrict__ Hst,                  // [2][2][Bq][Hq]
                float* __restrict__ Cst,                  // [2][Bq][Hq]
                unsigned* __restrict__ cnt,               // [16]
                void* __restrict__ out,                   // [M][512]
                int t0, int t1)
{
    extern __shared__ float lds[];
    float* Wl = lds;                    // [256][128]  k-major: Wl[k*128 + r]
    float* hl = Wl + 256 * 128;         // [256][8]    h staged: hl[k*8 + b]
    float* sc = hl + 256 * 8;           // [4][8][128] partials
    float* cl = sc + 4 * 8 * 128;       // [8][32]     c state

    const int tid = threadIdx.x;
    const int bid = blockIdx.x;
    const int js  = bid & 7;
    const int dir = (bid >> 3) & 1;
    const int bs  = bid >> 4;
    const int gix = bid >> 3;           // (bs,dir) group id 0..15
    const int j0 = js * 32, b0 = bs * 8;
    const float* Whh = dir ? Whh_b : Whh_f;

    // load Whh slice: local row r = g*32+jj  <->  global row g*256 + j0 + jj
    for (int idx = tid; idx < 128 * 256; idx += 512) {
        int rl = idx >> 8, k = idx & 255;
        int g = rl >> 5, jj = rl & 31;
        Wl[k * 128 + rl] = Whh[(size_t)(g * 256 + j0 + jj) * 256 + k];
    }
    const int rt = tid & 127, kt = tid >> 7;           // matvec roles
    const int ujj = tid & 31, ubb = (tid >> 5) & 7;    // update roles (tid<256)
    const bool l64 = (dflags[0] & 2u) != 0u;
    const int mylen = (int)(l64 ? len_u32[2 * (b0 + ubb)] : len_u32[b0 + ubb]);
    if (tid < 256) {
        float c0 = (t0 == 0) ? 0.f : Cst[((size_t)dir * Bq + b0 + ubb) * Hq + j0 + ujj];
        cl[ubb * 32 + ujj] = c0;
    }
    __syncthreads();

    for (int t = t0; t < t1; ++t) {
        const int teff = dir ? (Tq - 1 - t) : t;
        const int par = t & 1;
        // stage h[par] -> hl (agent-scope loads)
        {
            const int k = tid & 255, bh = tid >> 8;
            float* Hrd = Hst + (size_t)(par * 2 + dir) * Bq * Hq;
            #pragma unroll
            for (int i = 0; i < 4; ++i)
                hl[k * 8 + bh * 4 + i] =
                    __hip_atomic_load(&Hrd[(size_t)(b0 + bh * 4 + i) * Hq + k],
                                      __ATOMIC_RELAXED, __HIP_MEMORY_SCOPE_AGENT);
        }
        float xgv[4];
        if (tid < 256) {
            const float* xr = xg + ((size_t)(b0 + ubb) * Tq + teff) * 1024 + j0 + ujj;
            #pragma unroll
            for (int g = 0; g < 4; ++g) xgv[g] = xr[g * 256];
        }
        __syncthreads();
        // matvec partials: row rt, k-chunk kt, all 8 batch
        {
            float a0 = 0, a1 = 0, a2 = 0, a3 = 0, a4 = 0, a5 = 0, a6 = 0, a7 = 0;
            const int kbeg = kt * 64;
            #pragma unroll 4
            for (int k = kbeg; k < kbeg + 64; ++k) {
                float w = Wl[k * 128 + rt];
                float4 h0 = *(const float4*)(hl + k * 8);
                float4 h1 = *(const float4*)(hl + k * 8 + 4);
                a0 += w * h0.x; a1 += w * h0.y; a2 += w * h0.z; a3 += w * h0.w;
                a4 += w * h1.x; a5 += w * h1.y; a6 += w * h1.z; a7 += w * h1.w;
            }
            sc[(kt * 8 + 0) * 128 + rt] = a0;
            sc[(kt * 8 + 1) * 128 + rt] = a1;
            sc[(kt * 8 + 2) * 128 + rt] = a2;
            sc[(kt * 8 + 3) * 128 + rt] = a3;
            sc[(kt * 8 + 4) * 128 + rt] = a4;
            sc[(kt * 8 + 5) * 128 + rt] = a5;
            sc[(kt * 8 + 6) * 128 + rt] = a6;
            sc[(kt * 8 + 7) * 128 + rt] = a7;
        }
        __syncthreads();
        // gate update for (ujj, ubb)
        if (tid < 256) {
            float gv[4];
            #pragma unroll
            for (int g = 0; g < 4; ++g) {
                int r = g * 32 + ujj;
                float s = xgv[g];
                s += sc[(0 * 8 + ubb) * 128 + r];
                s += sc[(1 * 8 + ubb) * 128 + r];
                s += sc[(2 * 8 + ubb) * 128 + r];
                s += sc[(3 * 8 + ubb) * 128 + r];
                gv[g] = s;
            }
            float ig = sigmoidf_(gv[0]);
            float fg = sigmoidf_(gv[1]);
            float gg = tanhf(gv[2]);
            float og = sigmoidf_(gv[3]);
            float cold = cl[ubb * 32 + ujj];
            float cn = fg * cold + ig * gg;
            float hn = og * tanhf(cn);
            float hold = hl[(j0 + ujj) * 8 + ubb];
            bool m = (teff < mylen);
            float hm = m ? hn : hold;
            float cm = m ? cn : cold;
            cl[ubb * 32 + ujj] = cm;
            float* Hwr = Hst + ((size_t)((par ^ 1) * 2 + dir) * Bq + (b0 + ubb)) * Hq;
            __hip_atomic_store(&Hwr[j0 + ujj], hm,
                               __ATOMIC_RELAXED, __HIP_MEMORY_SCOPE_AGENT);
            size_t orow = (size_t)(b0 + ubb) * Tq + teff;
            if (OUTT == 1) ((_Float16*)out)[orow * 512 + dir * 256 + j0 + ujj] = (_Float16)hm;
            else           ((float*)out)[orow * 512 + dir * 256 + j0 + ujj] = hm;
        }
        __threadfence();
        __syncthreads();
        if (tid == 0) {
            __hip_atomic_fetch_add(&cnt[gix], 1u, __ATOMIC_ACQ_REL, __HIP_MEMORY_SCOPE_AGENT);
            const unsigned tgt = 8u * (unsigned)(t + 1);
            while (__hip_atomic_load(&cnt[gix], __ATOMIC_ACQUIRE, __HIP_MEMORY_SCOPE_AGENT) < tgt)
                __builtin_amdgcn_s_sleep(2);
        }
        __syncthreads();
        __threadfence();
    }
    // persist c for next phase
    if (tid < 256)
        Cst[((size_t)dir * Bq + b0 + ubb) * Hq + j0 + ujj] = cl[ubb * 32 + ujj];
}

extern "C" void kernel_launch(void* const* d_in, const int* in_sizes, int n_in,
                              void* d_out, int out_size, void* d_ws, size_t ws_size,
                              hipStream_t stream)
{
    const unsigned* words  = (const unsigned*)d_in[0];
    const unsigned* lens   = (const unsigned*)d_in[1];
    const float* emb     = (const float*)d_in[2];
    const float* l1f_Wih = (const float*)d_in[3];
    const float* l1f_Whh = (const float*)d_in[4];
    const float* l1f_bih = (const float*)d_in[5];
    const float* l1f_bhh = (const float*)d_in[6];
    const float* l1b_Wih = (const float*)d_in[7];
    const float* l1b_Whh = (const float*)d_in[8];
    const float* l1b_bih = (const float*)d_in[9];
    const float* l1b_bhh = (const float*)d_in[10];
    const float* l2f_Wih = (const float*)d_in[11];
    const float* l2f_Whh = (const float*)d_in[12];
    const float* l2f_bih = (const float*)d_in[13];
    const float* l2f_bhh = (const float*)d_in[14];
    const float* l2b_Wih = (const float*)d_in[15];
    const float* l2b_Whh = (const float*)d_in[16];
    const float* l2b_bih = (const float*)d_in[17];
    const float* l2b_bhh = (const float*)d_in[18];
    const float* cls_W   = (const float*)d_in[19];
    const float* cls_b   = (const float*)d_in[20];
    (void)in_sizes; (void)n_in; (void)out_size; (void)ws_size;

    char* ws = (char*)d_ws;
    size_t off = 0;
    auto alloc = [&](size_t b) { void* p = ws + off; off += (b + 255) & ~(size_t)255; return p; };
    float*     xg = (float*)alloc((size_t)Mq * 1024 * 4);   // 128 MiB, reused 4x
    float*     o1 = (float*)alloc((size_t)Mq * 512 * 4);    // 64 MiB
    _Float16*  o2 = (_Float16*)alloc((size_t)Mq * 512 * 2); // 32 MiB
    float*     H1 = (float*)alloc((size_t)2 * 2 * Bq * Hq * 4);
    float*     H2 = (float*)alloc((size_t)2 * 2 * Bq * Hq * 4);
    float*    Cst = (float*)alloc((size_t)2 * Bq * Hq * 4);
    float* biasbuf = (float*)alloc((size_t)4 * 1024 * 4);
    unsigned*  cnt = (unsigned*)alloc(32 * 4);
    unsigned* dflags = (unsigned*)alloc(256);

    const size_t ldsBytes = (size_t)(256 * 128 + 256 * 8 + 4 * 8 * 128 + 8 * 32) * sizeof(float);
    hipFuncSetAttribute((const void*)lstm_layer<0>, hipFuncAttributeMaxDynamicSharedMemorySize, (int)ldsBytes);
    hipFuncSetAttribute((const void*)lstm_layer<1>, hipFuncAttributeMaxDynamicSharedMemorySize, (int)ldsBytes);

    const float* b1f = biasbuf, *b1b = biasbuf + 1024, *b2f = biasbuf + 2048, *b2b = biasbuf + 3072;

    init_kernel<<<dim3(256), 256, 0, stream>>>(H1, H2, cnt);
    detect_int64<<<1, 256, 0, stream>>>(words, lens, dflags);
    bias_kernel<<<dim3(16), 256, 0, stream>>>(l1f_bih, l1f_bhh, l1b_bih, l1b_bhh,
                                              l2f_bih, l2f_bhh, l2b_bih, l2b_bhh, biasbuf);

    dim3 ggrid(1024 / 64, Mq / 64);
    // ---- layer 1 ----
    gemm_kernel<2, 0><<<ggrid, 256, 0, stream>>>(nullptr, words, emb, dflags,
        l1f_Wih, l1b_Wih, b1f, b1b, xg, Mq, 1024, Eq);
    lstm_layer<0><<<128, 512, ldsBytes, stream>>>(xg, l1f_Whh, l1b_Whh, lens, dflags, H1, Cst, cnt, o1, 0, 256);
    gemm_kernel<2, 0><<<ggrid, 256, 0, stream>>>(nullptr, words, emb, dflags,
        l1b_Wih, l1f_Wih, b1b, b1f, xg, Mq, 1024, Eq);
    lstm_layer<0><<<128, 512, ldsBytes, stream>>>(xg, l1f_Whh, l1b_Whh, lens, dflags, H1, Cst, cnt, o1, 256, 512);
    // ---- layer 2 ----
    gemm_kernel<0, 0><<<ggrid, 256, 0, stream>>>(o1, nullptr, nullptr, dflags,
        l2f_Wih, l2b_Wih, b2f, b2b, xg, Mq, 1024, 512);
    lstm_layer<1><<<128, 512, ldsBytes, stream>>>(xg, l2f_Whh, l2b_Whh, lens, dflags, H2, Cst, cnt + 16, o2, 0, 256);
    gemm_kernel<0, 0><<<ggrid, 256, 0, stream>>>(o1, nullptr, nullptr, dflags,
        l2b_Wih, l2f_Wih, b2b, b2f, xg, Mq, 1024, 512);
    lstm_layer<1><<<128, 512, ldsBytes, stream>>>(xg, l2f_Whh, l2b_Whh, lens, dflags, H2, Cst, cnt + 16, o2, 256, 512);
    // ---- classifier -> d_out (f32) ----
    gemm_kernel<3, 0><<<dim3(1, Mq / 64), 256, 0, stream>>>(o2, nullptr, nullptr, dflags,
        cls_W, cls_W, cls_b, cls_b, d_out, Mq, NTAGS, 512);
}

// Round 10
// 30464.621 us; speedup vs baseline: 1.3386x; 1.3386x over previous
//
#include <hip/hip_runtime.h>
#include <hip/hip_bf16.h>

#define Bq 64
#define Tq 512
#define Eq 128
#define Hq 256
#define NTAGS 50
#define Mq (Bq*Tq)   // 32768

__device__ __forceinline__ float sigmoidf_(float x) { return 1.f / (1.f + expf(-x)); }

// ---------------- dtype detection: int32 vs int64 for words/lengths ----------------
__global__ void detect_int64(const unsigned* __restrict__ words,
                             const unsigned* __restrict__ lens,
                             unsigned* __restrict__ dflags) {
    __shared__ int wbad, lbad, wnz, lnz;
    if (threadIdx.x == 0) { wbad = 0; lbad = 0; wnz = 0; lnz = 0; }
    __syncthreads();
    for (int i = threadIdx.x; i < 16384; i += blockDim.x) {
        if (words[2 * i + 1] != 0u) wbad = 1;
        if (words[2 * i] != 0u) wnz = 1;
    }
    for (int i = threadIdx.x; i < 32; i += blockDim.x) {
        if (lens[2 * i + 1] != 0u) lbad = 1;
        if (lens[2 * i] != 0u) lnz = 1;
    }
    __syncthreads();
    if (threadIdx.x == 0) {
        unsigned f = 0;
        if (!wbad && wnz) f |= 1u;
        if (!lbad && lnz) f |= 2u;
        dflags[0] = f;
    }
}

// ---------------- bias: bias[l][d][n] = bih + bhh ----------------
__global__ void bias_kernel(const float* b1f_ih, const float* b1f_hh,
                            const float* b1b_ih, const float* b1b_hh,
                            const float* b2f_ih, const float* b2f_hh,
                            const float* b2b_ih, const float* b2b_hh,
                            float* bias) {   // [4][1024]: l1f,l1b,l2f,l2b
    int i = blockIdx.x * blockDim.x + threadIdx.x;
    if (i >= 4096) return;
    int l = i >> 11, d = (i >> 10) & 1, nn = i & 1023;
    float v;
    if (l == 0) v = d ? (b1b_ih[nn] + b1b_hh[nn]) : (b1f_ih[nn] + b1f_hh[nn]);
    else        v = d ? (b2b_ih[nn] + b2b_hh[nn]) : (b2f_ih[nn] + b2f_hh[nn]);
    bias[i] = v;
}

// ---------------- Whh packing: W[1024][256] -> P[((hf*32+k4)*256+j)*16 + g*4 + kk] ----------------
// Lane j's 64B chunk holds the four float4s (g=0..3) for k = hf*128 + k4*4 .. +3.
__global__ void pack_whh(const float* __restrict__ W, float* __restrict__ P) {
    int t = blockIdx.x * 256 + threadIdx.x;   // 0..65535
    if (t >= 65536) return;
    int g = t & 3, j = (t >> 2) & 255, k4 = (t >> 10) & 31, hf = t >> 15;
    int row = g * 256 + j;
    int kbase = hf * 128 + k4 * 4;
    float4 v = *(const float4*)(W + (size_t)row * 256 + kbase);
    ((float4*)P)[t] = v;
}

// ---------------- f32 GEMM: C[M,N] = A[M,K] @ W[N,K]^T + bias (unchanged, passing) ----------------
// AMODE: 0 = A f32, 2 = A gathered from emb via words (dtype-adaptive), 3 = A f16
// OUTT:  0 = f32, 1 = f16
template<int AMODE, int OUTT>
__global__ __launch_bounds__(256)
void gemm_kernel(const void* __restrict__ Aptr, const unsigned* __restrict__ words_u32,
                 const float* __restrict__ emb, const unsigned* __restrict__ dflags,
                 const float* __restrict__ Wlo, const float* __restrict__ Whi,
                 const float* __restrict__ blo, const float* __restrict__ bhi,
                 void* __restrict__ Cptr, int M, int N, int K)
{
    __shared__ float As[16][68];
    __shared__ float Ws[16][68];
    const int tx = threadIdx.x & 15, ty = threadIdx.x >> 4;
    const int m0 = blockIdx.y * 64, n0 = blockIdx.x * 64;
    const bool hi = ((m0 & 511) >= 256);
    const float* W = hi ? Whi : Wlo;
    const float* bias = hi ? bhi : blo;
    const int lr = threadIdx.x >> 2, lc = threadIdx.x & 3;
    bool w64 = false;
    if (AMODE == 2) w64 = (dflags[0] & 1u) != 0u;
    float acc[4][4] = {};
    for (int k0 = 0; k0 < K; k0 += 16) {
        float a4[4], w4[4];
        if (AMODE == 2) {
            int m = m0 + lr;
            int w = (int)(w64 ? words_u32[2 * m] : words_u32[m]);
            float4 v = *(const float4*)(emb + (size_t)w * Eq + k0 + lc * 4);
            a4[0] = v.x; a4[1] = v.y; a4[2] = v.z; a4[3] = v.w;
        } else if (AMODE == 0) {
            float4 v = *(const float4*)((const float*)Aptr + (size_t)(m0 + lr) * K + k0 + lc * 4);
            a4[0] = v.x; a4[1] = v.y; a4[2] = v.z; a4[3] = v.w;
        } else {
            const _Float16* Ab = (const _Float16*)Aptr + (size_t)(m0 + lr) * K + k0 + lc * 4;
            #pragma unroll
            for (int q = 0; q < 4; ++q) a4[q] = (float)Ab[q];
        }
        int nrow = n0 + lr;
        if (nrow < N) {
            float4 v = *(const float4*)(W + (size_t)nrow * K + k0 + lc * 4);
            w4[0] = v.x; w4[1] = v.y; w4[2] = v.z; w4[3] = v.w;
        } else { w4[0] = w4[1] = w4[2] = w4[3] = 0.f; }
        __syncthreads();
        #pragma unroll
        for (int q = 0; q < 4; ++q) {
            As[lc * 4 + q][lr] = a4[q];
            Ws[lc * 4 + q][lr] = w4[q];
        }
        __syncthreads();
        #pragma unroll
        for (int kk = 0; kk < 16; ++kk) {
            float4 a = *(const float4*)&As[kk][ty * 4];
            float4 w = *(const float4*)&Ws[kk][tx * 4];
            float av[4] = {a.x, a.y, a.z, a.w};
            float wv[4] = {w.x, w.y, w.z, w.w};
            #pragma unroll
            for (int i = 0; i < 4; ++i)
                #pragma unroll
                for (int j = 0; j < 4; ++j)
                    acc[i][j] += av[i] * wv[j];
        }
    }
    #pragma unroll
    for (int i = 0; i < 4; ++i) {
        int row = m0 + ty * 4 + i;
        #pragma unroll
        for (int j = 0; j < 4; ++j) {
            int col = n0 + tx * 4 + j;
            if (col < N) {
                float v = acc[i][j] + bias[col];
                if (OUTT == 1) ((_Float16*)Cptr)[(size_t)row * N + col] = (_Float16)v;
                else           ((float*)Cptr)[(size_t)row * N + col] = v;
            }
        }
    }
}

// ---------------- wide zero-exchange LSTM: 1 block per (dir, batch-pair) ----------------
// 64 blocks x 1024 threads. thread = (b2 = tid>>9, hf = (tid>>8)&1, j = tid&255):
// computes rows {g*256+j} over k-half hf for batch b0+b2 from packed W (coalesced).
// h in LDS (broadcast reads), c in registers of tid<512. Zero cross-block traffic.
// OUTT: 0 = f32, 1 = f16
template<int OUTT>
__global__ __launch_bounds__(1024)
void lstm_wide(const float* __restrict__ xg,      // [M][1024] phased
               const float* __restrict__ Pf, const float* __restrict__ Pb, // packed Whh
               const unsigned* __restrict__ len_u32,
               const unsigned* __restrict__ dflags,
               float* __restrict__ Hsav,          // [2][Bq][Hq]
               float* __restrict__ Csav,          // [2][Bq][Hq]
               void* __restrict__ out,            // [M][512]
               int t0, int t1)
{
    __shared__ float hsh[2][256];
    __shared__ float sc[2][2][4][256];   // [b2][hf][g][j]

    const int tid = threadIdx.x;
    const int bid = blockIdx.x;
    const int dir = bid >> 5;
    const int b0 = (bid & 31) * 2;
    const int j = tid & 255;
    const int hf = (tid >> 8) & 1;
    const int b2 = tid >> 9;
    const float* __restrict__ P = dir ? Pb : Pf;
    const float* __restrict__ Ph = P + (size_t)hf * (32 * 256 * 16);
    const bool l64 = (dflags[0] & 2u) != 0u;

    float c = 0.f; int mylen = 0;
    if (tid < 512) {
        int ub2 = tid >> 8, b = b0 + ub2;
        mylen = (int)(l64 ? len_u32[2 * b] : len_u32[b]);
        if (t0 == 0) {
            hsh[ub2][j] = 0.f;
        } else {
            c = Csav[((size_t)dir * Bq + b) * Hq + j];
            hsh[ub2][j] = Hsav[((size_t)dir * Bq + b) * Hq + j];
        }
    }
    __syncthreads();

    for (int t = t0; t < t1; ++t) {
        const int teff = dir ? (Tq - 1 - t) : t;
        // early coalesced xg loads (update threads), consumed after matvec
        float xv0, xv1, xv2, xv3;
        if (tid < 512) {
            int ub2 = tid >> 8;
            const float* xr = xg + ((size_t)(b0 + ub2) * Tq + teff) * 1024 + j;
            xv0 = xr[0]; xv1 = xr[256]; xv2 = xr[512]; xv3 = xr[768];
        }
        // matvec: 4 gate rows, k-half, one batch
        float a0 = 0.f, a1 = 0.f, a2 = 0.f, a3 = 0.f;
        const float* hp = &hsh[b2][hf * 128];
        #pragma unroll 4
        for (int k4 = 0; k4 < 32; ++k4) {
            const float4* p = (const float4*)(Ph + ((size_t)k4 * 256 + j) * 16);
            float4 hv = *(const float4*)(hp + k4 * 4);
            float4 w0 = p[0], w1 = p[1], w2 = p[2], w3 = p[3];
            a0 += w0.x * hv.x + w0.y * hv.y + w0.z * hv.z + w0.w * hv.w;
            a1 += w1.x * hv.x + w1.y * hv.y + w1.z * hv.z + w1.w * hv.w;
            a2 += w2.x * hv.x + w2.y * hv.y + w2.z * hv.z + w2.w * hv.w;
            a3 += w3.x * hv.x + w3.y * hv.y + w3.z * hv.z + w3.w * hv.w;
        }
        sc[b2][hf][0][j] = a0;
        sc[b2][hf][1][j] = a1;
        sc[b2][hf][2][j] = a2;
        sc[b2][hf][3][j] = a3;
        __syncthreads();
        if (tid < 512) {
            int ub2 = tid >> 8;
            float g0 = xv0 + sc[ub2][0][0][j] + sc[ub2][1][0][j];
            float g1 = xv1 + sc[ub2][0][1][j] + sc[ub2][1][1][j];
            float g2 = xv2 + sc[ub2][0][2][j] + sc[ub2][1][2][j];
            float g3 = xv3 + sc[ub2][0][3][j] + sc[ub2][1][3][j];
            float ig = sigmoidf_(g0);
            float fg = sigmoidf_(g1);
            float gg = tanhf(g2);
            float og = sigmoidf_(g3);
            float cn = fg * c + ig * gg;
            float hn = og * tanhf(cn);
            bool m = (teff < mylen);
            float hold = hsh[ub2][j];
            float hm = m ? hn : hold;
            c = m ? cn : c;
            hsh[ub2][j] = hm;
            size_t orow = (size_t)(b0 + ub2) * Tq + teff;
            if (OUTT == 1) ((_Float16*)out)[orow * 512 + dir * 256 + j] = (_Float16)hm;
            else           ((float*)out)[orow * 512 + dir * 256 + j] = hm;
        }
        __syncthreads();
    }
    if (tid < 512) {
        int ub2 = tid >> 8, b = b0 + ub2;
        Csav[((size_t)dir * Bq + b) * Hq + j] = c;
        Hsav[((size_t)dir * Bq + b) * Hq + j] = hsh[ub2][j];
    }
}

extern "C" void kernel_launch(void* const* d_in, const int* in_sizes, int n_in,
                              void* d_out, int out_size, void* d_ws, size_t ws_size,
                              hipStream_t stream)
{
    const unsigned* words  = (const unsigned*)d_in[0];
    const unsigned* lens   = (const unsigned*)d_in[1];
    const float* emb     = (const float*)d_in[2];
    const float* l1f_Wih = (const float*)d_in[3];
    const float* l1f_Whh = (const float*)d_in[4];
    const float* l1f_bih = (const float*)d_in[5];
    const float* l1f_bhh = (const float*)d_in[6];
    const float* l1b_Wih = (const float*)d_in[7];
    const float* l1b_Whh = (const float*)d_in[8];
    const float* l1b_bih = (const float*)d_in[9];
    const float* l1b_bhh = (const float*)d_in[10];
    const float* l2f_Wih = (const float*)d_in[11];
    const float* l2f_Whh = (const float*)d_in[12];
    const float* l2f_bih = (const float*)d_in[13];
    const float* l2f_bhh = (const float*)d_in[14];
    const float* l2b_Wih = (const float*)d_in[15];
    const float* l2b_Whh = (const float*)d_in[16];
    const float* l2b_bih = (const float*)d_in[17];
    const float* l2b_bhh = (const float*)d_in[18];
    const float* cls_W   = (const float*)d_in[19];
    const float* cls_b   = (const float*)d_in[20];
    (void)in_sizes; (void)n_in; (void)out_size; (void)ws_size;

    char* ws = (char*)d_ws;
    size_t off = 0;
    auto alloc = [&](size_t b) { void* p = ws + off; off += (b + 255) & ~(size_t)255; return p; };
    float*     xg = (float*)alloc((size_t)Mq * 1024 * 4);   // 128 MiB, reused 4x
    float*     o1 = (float*)alloc((size_t)Mq * 512 * 4);    // 64 MiB
    _Float16*  o2 = (_Float16*)alloc((size_t)Mq * 512 * 2); // 32 MiB
    float*   Wpk = (float*)alloc((size_t)4 * 1024 * 256 * 4); // 4 MiB packed Whh
    float*   Hsav = (float*)alloc((size_t)2 * Bq * Hq * 4);
    float*   Csav = (float*)alloc((size_t)2 * Bq * Hq * 4);
    float* biasbuf = (float*)alloc((size_t)4 * 1024 * 4);
    unsigned* dflags = (unsigned*)alloc(256);
    // total ~228.5 MiB

    const float* b1f = biasbuf, *b1b = biasbuf + 1024, *b2f = biasbuf + 2048, *b2b = biasbuf + 3072;
    float* P1f = Wpk, *P1b = Wpk + 262144, *P2f = Wpk + 2 * 262144, *P2b = Wpk + 3 * 262144;

    detect_int64<<<1, 256, 0, stream>>>(words, lens, dflags);
    bias_kernel<<<dim3(16), 256, 0, stream>>>(l1f_bih, l1f_bhh, l1b_bih, l1b_bhh,
                                              l2f_bih, l2f_bhh, l2b_bih, l2b_bhh, biasbuf);
    pack_whh<<<dim3(256), 256, 0, stream>>>(l1f_Whh, P1f);
    pack_whh<<<dim3(256), 256, 0, stream>>>(l1b_Whh, P1b);
    pack_whh<<<dim3(256), 256, 0, stream>>>(l2f_Whh, P2f);
    pack_whh<<<dim3(256), 256, 0, stream>>>(l2b_Whh, P2b);

    dim3 ggrid(1024 / 64, Mq / 64);
    // ---- layer 1 ----
    gemm_kernel<2, 0><<<ggrid, 256, 0, stream>>>(nullptr, words, emb, dflags,
        l1f_Wih, l1b_Wih, b1f, b1b, xg, Mq, 1024, Eq);
    lstm_wide<0><<<64, 1024, 0, stream>>>(xg, P1f, P1b, lens, dflags, Hsav, Csav, o1, 0, 256);
    gemm_kernel<2, 0><<<ggrid, 256, 0, stream>>>(nullptr, words, emb, dflags,
        l1b_Wih, l1f_Wih, b1b, b1f, xg, Mq, 1024, Eq);
    lstm_wide<0><<<64, 1024, 0, stream>>>(xg, P1f, P1b, lens, dflags, Hsav, Csav, o1, 256, 512);
    // ---- layer 2 ----
    gemm_kernel<0, 0><<<ggrid, 256, 0, stream>>>(o1, nullptr, nullptr, dflags,
        l2f_Wih, l2b_Wih, b2f, b2b, xg, Mq, 1024, 512);
    lstm_wide<1><<<64, 1024, 0, stream>>>(xg, P2f, P2b, lens, dflags, Hsav, Csav, o2, 0, 256);
    gemm_kernel<0, 0><<<ggrid, 256, 0, stream>>>(o1, nullptr, nullptr, dflags,
        l2b_Wih, l2f_Wih, b2b, b2f, xg, Mq, 1024, 512);
    lstm_wide<1><<<64, 1024, 0, stream>>>(xg, P2f, P2b, lens, dflags, Hsav, Csav, o2, 256, 512);
    // ---- classifier -> d_out (f32) ----
    gemm_kernel<3, 0><<<dim3(1, Mq / 64), 256, 0, stream>>>(o2, nullptr, nullptr, dflags,
        cls_W, cls_W, cls_b, cls_b, d_out, Mq, NTAGS, 512);
}

// Round 11
// 16882.524 us; speedup vs baseline: 2.4156x; 1.8045x over previous
//
#include <hip/hip_runtime.h>
#include <hip/hip_bf16.h>

#define Bq 64
#define Tq 512
#define Eq 128
#define Hq 256
#define NTAGS 50
#define Mq (Bq*Tq)   // 32768

__device__ __forceinline__ float sigmoidf_(float x) { return 1.f / (1.f + expf(-x)); }

// ---------------- dtype detection: int32 vs int64 for words/lengths ----------------
__global__ void detect_int64(const unsigned* __restrict__ words,
                             const unsigned* __restrict__ lens,
                             unsigned* __restrict__ dflags) {
    __shared__ int wbad, lbad, wnz, lnz;
    if (threadIdx.x == 0) { wbad = 0; lbad = 0; wnz = 0; lnz = 0; }
    __syncthreads();
    for (int i = threadIdx.x; i < 16384; i += blockDim.x) {
        if (words[2 * i + 1] != 0u) wbad = 1;
        if (words[2 * i] != 0u) wnz = 1;
    }
    for (int i = threadIdx.x; i < 32; i += blockDim.x) {
        if (lens[2 * i + 1] != 0u) lbad = 1;
        if (lens[2 * i] != 0u) lnz = 1;
    }
    __syncthreads();
    if (threadIdx.x == 0) {
        unsigned f = 0;
        if (!wbad && wnz) f |= 1u;
        if (!lbad && lnz) f |= 2u;
        dflags[0] = f;
    }
}

// ---------------- bias: bias[l][d][n] = bih + bhh ----------------
__global__ void bias_kernel(const float* b1f_ih, const float* b1f_hh,
                            const float* b1b_ih, const float* b1b_hh,
                            const float* b2f_ih, const float* b2f_hh,
                            const float* b2b_ih, const float* b2b_hh,
                            float* bias) {   // [4][1024]: l1f,l1b,l2f,l2b
    int i = blockIdx.x * blockDim.x + threadIdx.x;
    if (i >= 4096) return;
    int l = i >> 11, d = (i >> 10) & 1, nn = i & 1023;
    float v;
    if (l == 0) v = d ? (b1b_ih[nn] + b1b_hh[nn]) : (b1f_ih[nn] + b1f_hh[nn]);
    else        v = d ? (b2b_ih[nn] + b2b_hh[nn]) : (b2f_ih[nn] + b2f_hh[nn]);
    bias[i] = v;
}

// ---------------- Whh packing: W[1024][256] -> P[((hf*32+k4)*256+j)*16 + g*4 + kk] ----------------
__global__ void pack_whh(const float* __restrict__ W, float* __restrict__ P) {
    int t = blockIdx.x * 256 + threadIdx.x;   // 0..65535
    if (t >= 65536) return;
    int g = t & 3, j = (t >> 2) & 255, k4 = (t >> 10) & 31, hf = t >> 15;
    int row = g * 256 + j;
    int kbase = hf * 128 + k4 * 4;
    float4 v = *(const float4*)(W + (size_t)row * 256 + kbase);
    ((float4*)P)[t] = v;
}

// ---------------- f32 GEMM: C[M,N] = A[M,K] @ W[N,K]^T + bias (unchanged, passing) ----------------
// AMODE: 0 = A f32, 2 = A gathered from emb via words (dtype-adaptive), 3 = A f16
// OUTT:  0 = f32, 1 = f16
template<int AMODE, int OUTT>
__global__ __launch_bounds__(256)
void gemm_kernel(const void* __restrict__ Aptr, const unsigned* __restrict__ words_u32,
                 const float* __restrict__ emb, const unsigned* __restrict__ dflags,
                 const float* __restrict__ Wlo, const float* __restrict__ Whi,
                 const float* __restrict__ blo, const float* __restrict__ bhi,
                 void* __restrict__ Cptr, int M, int N, int K)
{
    __shared__ float As[16][68];
    __shared__ float Ws[16][68];
    const int tx = threadIdx.x & 15, ty = threadIdx.x >> 4;
    const int m0 = blockIdx.y * 64, n0 = blockIdx.x * 64;
    const bool hi = ((m0 & 511) >= 256);
    const float* W = hi ? Whi : Wlo;
    const float* bias = hi ? bhi : blo;
    const int lr = threadIdx.x >> 2, lc = threadIdx.x & 3;
    bool w64 = false;
    if (AMODE == 2) w64 = (dflags[0] & 1u) != 0u;
    float acc[4][4] = {};
    for (int k0 = 0; k0 < K; k0 += 16) {
        float a4[4], w4[4];
        if (AMODE == 2) {
            int m = m0 + lr;
            int w = (int)(w64 ? words_u32[2 * m] : words_u32[m]);
            float4 v = *(const float4*)(emb + (size_t)w * Eq + k0 + lc * 4);
            a4[0] = v.x; a4[1] = v.y; a4[2] = v.z; a4[3] = v.w;
        } else if (AMODE == 0) {
            float4 v = *(const float4*)((const float*)Aptr + (size_t)(m0 + lr) * K + k0 + lc * 4);
            a4[0] = v.x; a4[1] = v.y; a4[2] = v.z; a4[3] = v.w;
        } else {
            const _Float16* Ab = (const _Float16*)Aptr + (size_t)(m0 + lr) * K + k0 + lc * 4;
            #pragma unroll
            for (int q = 0; q < 4; ++q) a4[q] = (float)Ab[q];
        }
        int nrow = n0 + lr;
        if (nrow < N) {
            float4 v = *(const float4*)(W + (size_t)nrow * K + k0 + lc * 4);
            w4[0] = v.x; w4[1] = v.y; w4[2] = v.z; w4[3] = v.w;
        } else { w4[0] = w4[1] = w4[2] = w4[3] = 0.f; }
        __syncthreads();
        #pragma unroll
        for (int q = 0; q < 4; ++q) {
            As[lc * 4 + q][lr] = a4[q];
            Ws[lc * 4 + q][lr] = w4[q];
        }
        __syncthreads();
        #pragma unroll
        for (int kk = 0; kk < 16; ++kk) {
            float4 a = *(const float4*)&As[kk][ty * 4];
            float4 w = *(const float4*)&Ws[kk][tx * 4];
            float av[4] = {a.x, a.y, a.z, a.w};
            float wv[4] = {w.x, w.y, w.z, w.w};
            #pragma unroll
            for (int i = 0; i < 4; ++i)
                #pragma unroll
                for (int j = 0; j < 4; ++j)
                    acc[i][j] += av[i] * wv[j];
        }
    }
    #pragma unroll
    for (int i = 0; i < 4; ++i) {
        int row = m0 + ty * 4 + i;
        #pragma unroll
        for (int j = 0; j < 4; ++j) {
            int col = n0 + tx * 4 + j;
            if (col < N) {
                float v = acc[i][j] + bias[col];
                if (OUTT == 1) ((_Float16*)Cptr)[(size_t)row * N + col] = (_Float16)v;
                else           ((float*)Cptr)[(size_t)row * N + col] = v;
            }
        }
    }
}

// ---------------- 4-batch zero-exchange LSTM: 1 block per (dir, batch-quad) ----------------
// 32 blocks x 512 threads. thread = (hf = tid>>8, j = tid&255): computes gate rows
// {g*256+j} over k-half hf for ALL 4 batches from packed W (one 1MB W stream
// amortized over 4 batches). h in LDS (b128 broadcast), c in registers
// (2 update-units per thread). Zero cross-block traffic.
// OUTT: 0 = f32, 1 = f16
template<int OUTT>
__global__ __launch_bounds__(512)
void lstm_nb4(const float* __restrict__ xg,      // [M][1024] phased
              const float* __restrict__ Pf, const float* __restrict__ Pb, // packed Whh
              const unsigned* __restrict__ len_u32,
              const unsigned* __restrict__ dflags,
              float* __restrict__ Hsav,          // [2][Bq][Hq]
              float* __restrict__ Csav,          // [2][Bq][Hq]
              void* __restrict__ out,            // [M][512]
              int t0, int t1)
{
    __shared__ float hsh[4][256];
    __shared__ float scr[2][4][4][256];   // [hf][b][g][j]

    const int tid = threadIdx.x;
    const int bid = blockIdx.x;
    const int dir = bid >> 4;
    const int b0  = (bid & 15) * 4;
    const int j   = tid & 255;
    const int hf  = tid >> 8;
    const float* __restrict__ P  = dir ? Pb : Pf;
    const float* __restrict__ Ph = P + (size_t)hf * (32 * 256 * 16);
    const bool l64 = (dflags[0] & 2u) != 0u;

    // update units: u0 = (bu0, j), u1 = (bu1, j)
    const int bu0 = tid >> 8;         // 0..1
    const int bu1 = bu0 + 2;          // 2..3
    const int mylen0 = (int)(l64 ? len_u32[2 * (b0 + bu0)] : len_u32[b0 + bu0]);
    const int mylen1 = (int)(l64 ? len_u32[2 * (b0 + bu1)] : len_u32[b0 + bu1]);

    float c0 = 0.f, c1 = 0.f;
    if (t0 == 0) {
        hsh[bu0][j] = 0.f;
        hsh[bu1][j] = 0.f;
    } else {
        c0 = Csav[((size_t)dir * Bq + b0 + bu0) * Hq + j];
        c1 = Csav[((size_t)dir * Bq + b0 + bu1) * Hq + j];
        hsh[bu0][j] = Hsav[((size_t)dir * Bq + b0 + bu0) * Hq + j];
        hsh[bu1][j] = Hsav[((size_t)dir * Bq + b0 + bu1) * Hq + j];
    }
    __syncthreads();

    for (int t = t0; t < t1; ++t) {
        const int teff = dir ? (Tq - 1 - t) : t;
        // prefetch xg for both update units (consumed after matvec)
        const float* xr0 = xg + ((size_t)(b0 + bu0) * Tq + teff) * 1024 + j;
        const float* xr1 = xg + ((size_t)(b0 + bu1) * Tq + teff) * 1024 + j;
        float xv0[4], xv1[4];
        #pragma unroll
        for (int g = 0; g < 4; ++g) { xv0[g] = xr0[g * 256]; xv1[g] = xr1[g * 256]; }

        // matvec: 4 gate rows x 4 batches over k-half hf
        float a[4][4] = {};   // [g][b]
        #pragma unroll 4
        for (int k4 = 0; k4 < 32; ++k4) {
            const float4* p = (const float4*)(Ph + ((size_t)k4 * 256 + j) * 16);
            float4 w0 = p[0], w1 = p[1], w2 = p[2], w3 = p[3];
            #pragma unroll
            for (int b = 0; b < 4; ++b) {
                float4 hv = *(const float4*)(&hsh[b][hf * 128 + k4 * 4]);
                a[0][b] += w0.x * hv.x + w0.y * hv.y + w0.z * hv.z + w0.w * hv.w;
                a[1][b] += w1.x * hv.x + w1.y * hv.y + w1.z * hv.z + w1.w * hv.w;
                a[2][b] += w2.x * hv.x + w2.y * hv.y + w2.z * hv.z + w2.w * hv.w;
                a[3][b] += w3.x * hv.x + w3.y * hv.y + w3.z * hv.z + w3.w * hv.w;
            }
        }
        #pragma unroll
        for (int b = 0; b < 4; ++b)
            #pragma unroll
            for (int g = 0; g < 4; ++g)
                scr[hf][b][g][j] = a[g][b];
        __syncthreads();

        // update both units
        {
            float g0 = xv0[0] + scr[0][bu0][0][j] + scr[1][bu0][0][j];
            float g1 = xv0[1] + scr[0][bu0][1][j] + scr[1][bu0][1][j];
            float g2 = xv0[2] + scr[0][bu0][2][j] + scr[1][bu0][2][j];
            float g3 = xv0[3] + scr[0][bu0][3][j] + scr[1][bu0][3][j];
            float ig = sigmoidf_(g0), fg = sigmoidf_(g1);
            float gg = tanhf(g2), og = sigmoidf_(g3);
            float cn = fg * c0 + ig * gg;
            float hn = og * tanhf(cn);
            bool m = (teff < mylen0);
            float hold = hsh[bu0][j];
            float hm = m ? hn : hold;
            c0 = m ? cn : c0;
            hsh[bu0][j] = hm;
            size_t orow = (size_t)(b0 + bu0) * Tq + teff;
            if (OUTT == 1) ((_Float16*)out)[orow * 512 + dir * 256 + j] = (_Float16)hm;
            else           ((float*)out)[orow * 512 + dir * 256 + j] = hm;
        }
        {
            float g0 = xv1[0] + scr[0][bu1][0][j] + scr[1][bu1][0][j];
            float g1 = xv1[1] + scr[0][bu1][1][j] + scr[1][bu1][1][j];
            float g2 = xv1[2] + scr[0][bu1][2][j] + scr[1][bu1][2][j];
            float g3 = xv1[3] + scr[0][bu1][3][j] + scr[1][bu1][3][j];
            float ig = sigmoidf_(g0), fg = sigmoidf_(g1);
            float gg = tanhf(g2), og = sigmoidf_(g3);
            float cn = fg * c1 + ig * gg;
            float hn = og * tanhf(cn);
            bool m = (teff < mylen1);
            float hold = hsh[bu1][j];
            float hm = m ? hn : hold;
            c1 = m ? cn : c1;
            hsh[bu1][j] = hm;
            size_t orow = (size_t)(b0 + bu1) * Tq + teff;
            if (OUTT == 1) ((_Float16*)out)[orow * 512 + dir * 256 + j] = (_Float16)hm;
            else           ((float*)out)[orow * 512 + dir * 256 + j] = hm;
        }
        __syncthreads();
    }
    Csav[((size_t)dir * Bq + b0 + bu0) * Hq + j] = c0;
    Csav[((size_t)dir * Bq + b0 + bu1) * Hq + j] = c1;
    Hsav[((size_t)dir * Bq + b0 + bu0) * Hq + j] = hsh[bu0][j];
    Hsav[((size_t)dir * Bq + b0 + bu1) * Hq + j] = hsh[bu1][j];
}

extern "C" void kernel_launch(void* const* d_in, const int* in_sizes, int n_in,
                              void* d_out, int out_size, void* d_ws, size_t ws_size,
                              hipStream_t stream)
{
    const unsigned* words  = (const unsigned*)d_in[0];
    const unsigned* lens   = (const unsigned*)d_in[1];
    const float* emb     = (const float*)d_in[2];
    const float* l1f_Wih = (const float*)d_in[3];
    const float* l1f_Whh = (const float*)d_in[4];
    const float* l1f_bih = (const float*)d_in[5];
    const float* l1f_bhh = (const float*)d_in[6];
    const float* l1b_Wih = (const float*)d_in[7];
    const float* l1b_Whh = (const float*)d_in[8];
    const float* l1b_bih = (const float*)d_in[9];
    const float* l1b_bhh = (const float*)d_in[10];
    const float* l2f_Wih = (const float*)d_in[11];
    const float* l2f_Whh = (const float*)d_in[12];
    const float* l2f_bih = (const float*)d_in[13];
    const float* l2f_bhh = (const float*)d_in[14];
    const float* l2b_Wih = (const float*)d_in[15];
    const float* l2b_Whh = (const float*)d_in[16];
    const float* l2b_bih = (const float*)d_in[17];
    const float* l2b_bhh = (const float*)d_in[18];
    const float* cls_W   = (const float*)d_in[19];
    const float* cls_b   = (const float*)d_in[20];
    (void)in_sizes; (void)n_in; (void)out_size; (void)ws_size;

    char* ws = (char*)d_ws;
    size_t off = 0;
    auto alloc = [&](size_t b) { void* p = ws + off; off += (b + 255) & ~(size_t)255; return p; };
    float*     xg = (float*)alloc((size_t)Mq * 1024 * 4);   // 128 MiB, reused 4x
    float*     o1 = (float*)alloc((size_t)Mq * 512 * 4);    // 64 MiB
    _Float16*  o2 = (_Float16*)alloc((size_t)Mq * 512 * 2); // 32 MiB
    float*   Wpk = (float*)alloc((size_t)4 * 1024 * 256 * 4); // 4 MiB packed Whh
    float*   Hsav = (float*)alloc((size_t)2 * Bq * Hq * 4);
    float*   Csav = (float*)alloc((size_t)2 * Bq * Hq * 4);
    float* biasbuf = (float*)alloc((size_t)4 * 1024 * 4);
    unsigned* dflags = (unsigned*)alloc(256);

    const float* b1f = biasbuf, *b1b = biasbuf + 1024, *b2f = biasbuf + 2048, *b2b = biasbuf + 3072;
    float* P1f = Wpk, *P1b = Wpk + 262144, *P2f = Wpk + 2 * 262144, *P2b = Wpk + 3 * 262144;

    detect_int64<<<1, 256, 0, stream>>>(words, lens, dflags);
    bias_kernel<<<dim3(16), 256, 0, stream>>>(l1f_bih, l1f_bhh, l1b_bih, l1b_bhh,
                                              l2f_bih, l2f_bhh, l2b_bih, l2b_bhh, biasbuf);
    pack_whh<<<dim3(256), 256, 0, stream>>>(l1f_Whh, P1f);
    pack_whh<<<dim3(256), 256, 0, stream>>>(l1b_Whh, P1b);
    pack_whh<<<dim3(256), 256, 0, stream>>>(l2f_Whh, P2f);
    pack_whh<<<dim3(256), 256, 0, stream>>>(l2b_Whh, P2b);

    dim3 ggrid(1024 / 64, Mq / 64);
    // ---- layer 1 ----
    gemm_kernel<2, 0><<<ggrid, 256, 0, stream>>>(nullptr, words, emb, dflags,
        l1f_Wih, l1b_Wih, b1f, b1b, xg, Mq, 1024, Eq);
    lstm_nb4<0><<<32, 512, 0, stream>>>(xg, P1f, P1b, lens, dflags, Hsav, Csav, o1, 0, 256);
    gemm_kernel<2, 0><<<ggrid, 256, 0, stream>>>(nullptr, words, emb, dflags,
        l1b_Wih, l1f_Wih, b1b, b1f, xg, Mq, 1024, Eq);
    lstm_nb4<0><<<32, 512, 0, stream>>>(xg, P1f, P1b, lens, dflags, Hsav, Csav, o1, 256, 512);
    // ---- layer 2 ----
    gemm_kernel<0, 0><<<ggrid, 256, 0, stream>>>(o1, nullptr, nullptr, dflags,
        l2f_Wih, l2b_Wih, b2f, b2b, xg, Mq, 1024, 512);
    lstm_nb4<1><<<32, 512, 0, stream>>>(xg, P2f, P2b, lens, dflags, Hsav, Csav, o2, 0, 256);
    gemm_kernel<0, 0><<<ggrid, 256, 0, stream>>>(o1, nullptr, nullptr, dflags,
        l2b_Wih, l2f_Wih, b2b, b2f, xg, Mq, 1024, 512);
    lstm_nb4<1><<<32, 512, 0, stream>>>(xg, P2f, P2b, lens, dflags, Hsav, Csav, o2, 256, 512);
    // ---- classifier -> d_out (f32) ----
    gemm_kernel<3, 0><<<dim3(1, Mq / 64), 256, 0, stream>>>(o2, nullptr, nullptr, dflags,
        cls_W, cls_W, cls_b, cls_b, d_out, Mq, NTAGS, 512);
}